// Round 10
// baseline (428.520 us; speedup 1.0000x reference)
//
#include <hip/hip_runtime.h>
#include <hip/hip_bf16.h>

#define DD 512
#define HDIM 64
#define NROWS 131072

typedef __bf16 bf16x8 __attribute__((ext_vector_type(8)));
typedef float f32x4 __attribute__((ext_vector_type(4)));

static __device__ __forceinline__ unsigned bfbits(float f) {
    union { float f; unsigned u; } x; x.f = f;
    unsigned r = x.u + 0x7fffu + ((x.u >> 16) & 1u);
    return r >> 16;
}
static __device__ __forceinline__ __bf16 to_bf16(float f) {
    union { unsigned short s; __bf16 b; } y; y.s = (unsigned short)bfbits(f); return y.b;
}

// Fragment-linear byte offset for a [512 cols][512 k] bf16 weight matrix:
// tile (c>>6, k>>5, (c>>4)&3) of 1024B; within: slot=((k>>3)&3)*16+(c&15), elem k&7.
static __device__ __forceinline__ size_t fragoff(int c, int d) {
    return (size_t)((((c >> 6) * 64 + (d >> 5) * 4 + ((c >> 4) & 3)) << 10)
         + (((((d >> 3) & 3) << 4) + (c & 15)) << 4) + ((d & 7) << 1));
}

static __device__ __forceinline__ void gll16(const void* gsrc, void* ldst) {
    __builtin_amdgcn_global_load_lds(
        (const __attribute__((address_space(1))) unsigned int*)gsrc,
        (__attribute__((address_space(3))) unsigned int*)ldst, 16, 0, 0);
}

#define VMCNT(n) asm volatile("s_waitcnt vmcnt(" #n ")" ::: "memory")

// bijective XCD-chunk swizzle (m204)
static __device__ __forceinline__ int xcd_swz(int bid, int nwg) {
    const int q = nwg >> 3, r = nwg & 7;
    const int xcd = bid & 7, idx = bid >> 3;
    return (xcd < r ? xcd * (q + 1) : r * (q + 1) + (xcd - r) * q) + idx;
}

// ---------------- prep 1: k/v projections of memory (tiny) ----------------
__global__ void prep_kv(const float* __restrict__ memory,
                        const float* __restrict__ Wk, const float* __restrict__ bk,
                        const float* __restrict__ Wv, const float* __restrict__ bv,
                        float* __restrict__ kproj, float* __restrict__ vproj) {
    __shared__ float mrow[DD];
    const int m = blockIdx.x;
    const int t = threadIdx.x;
    for (int i = t; i < DD; i += 256) mrow[i] = memory[(size_t)m * DD + i];
    __syncthreads();
    for (int jj = 0; jj < 2; ++jj) {
        const int j = t + jj * 256;
        const float* wkr = Wk + (size_t)j * DD;
        const float* wvr = Wv + (size_t)j * DD;
        float sk = 0.f, sv = 0.f;
        for (int d = 0; d < DD; ++d) {
            const float md = mrow[d];
            sk += md * wkr[d];
            sv += md * wvr[d];
        }
        kproj[(size_t)m * DD + j] = sk + bk[j];
        vproj[(size_t)m * DD + j] = sv + bv[j];
    }
}

// ---------------- prep 2: fold into W2fr / b2 / W3fr (fragment-linear) -------
__global__ void prep_w(const float* __restrict__ Wq, const float* __restrict__ bq,
                       const float* __restrict__ Wo,
                       const float* __restrict__ kproj, const float* __restrict__ vproj,
                       __bf16* __restrict__ W2fr, float* __restrict__ b2,
                       __bf16* __restrict__ W3fr) {
    const int i = blockIdx.x;   // c (score-col) for W2fr/b2; j (out-col) for W3fr
    const int t = threadIdx.x;
    __shared__ float kp[HDIM];
    __shared__ float worow[DD];
    const int m = i & 63, h = i >> 6;
    if (t < HDIM) kp[t] = kproj[(size_t)m * DD + h * HDIM + t];
    for (int d = t; d < DD; d += 256) worow[d] = Wo[(size_t)i * DD + d];
    __syncthreads();
    for (int dd2 = 0; dd2 < 2; ++dd2) {
        const int d = t + dd2 * 256;
        float s = 0.f;
        #pragma unroll 8
        for (int hd = 0; hd < HDIM; ++hd)
            s += Wq[(size_t)(h * HDIM + hd) * DD + d] * kp[hd];
        *(__bf16*)((char*)W2fr + fragoff(i, d)) = to_bf16(s);
    }
    if (t == 0) {
        float s = 0.f;
        for (int hd = 0; hd < HDIM; ++hd) s += bq[h * HDIM + hd] * kp[hd];
        b2[i] = s;
    }
    for (int cc = 0; cc < 2; ++cc) {
        const int c = t + cc * 256;
        const int mc = c & 63, hc = c >> 6;
        float s = 0.f;
        #pragma unroll 8
        for (int hd = 0; hd < HDIM; ++hd)
            s += vproj[(size_t)mc * DD + hc * HDIM + hd] * worow[hc * HDIM + hd];
        *(__bf16*)((char*)W3fr + fragoff(i, c)) = to_bf16(s);
    }
}

// ---------------- kernel 1: S = x@W2 + b2, softmax -> attn_p (frag order) -----
// Block: 128 rows x 1 head (nt=head); 4 waves, wave = 32 rows x 64 cols.
// acc[2][4]=32 AGPR -> launch_bounds(256,4) targets 16 waves/CU.
__global__ __launch_bounds__(256, 4) void k1_gemm_sm(
    const float* __restrict__ x, const int* __restrict__ mask,
    const __bf16* __restrict__ W2fr, const float* __restrict__ b2,
    __bf16* __restrict__ attn_p, int row0) {
    __shared__ char ldsb[32768];   // A fp32 dbuf: 0 / 16384

    const int tid = threadIdx.x;
    const int lane = tid & 63;
    const int wr = tid >> 6;          // 0..3 = 32-row strip
    const int lc = lane & 15, grp = lane >> 4;
    const int swz = xcd_swz(blockIdx.x, gridDim.x);
    const int h = swz & 7, rt = swz >> 3;
    const int gr0 = row0 + rt * 128;

    const char* bbase = (const char*)W2fr + (size_t)h * 65536 + lane * 16;

    // A-gll per-lane source (inverse of the fp32 bank swizzle)
    const float* psA[4];
    #pragma unroll
    for (int i = 0; i < 4; ++i) {
        const int G = i * 256 + tid;
        const int rowA = G >> 3;
        const int gA = (G & 7) ^ (rowA & 7);
        psA[i] = x + (size_t)(gr0 + rowA) * DD + gA * 4;
    }

    #define STAGEA(kt, buf)                                                        \
        { _Pragma("unroll")                                                        \
          for (int i = 0; i < 4; ++i)                                              \
              gll16(psA[i] + (kt) * 32, ldsb + (buf) * 16384 + i * 4096 + wr * 1024); }
    #define LOADB1(kt, buf)                                                        \
        { _Pragma("unroll")                                                        \
          for (int n = 0; n < 4; ++n)                                              \
              bb[buf][n] = *(const bf16x8*)(bbase + ((kt) * 4 + n) * 1024); }

    bf16x8 bb[2][4];
    f32x4 acc[2][4];
    #pragma unroll
    for (int m = 0; m < 2; ++m)
        #pragma unroll
        for (int n = 0; n < 4; ++n) acc[m][n] = (f32x4){0.f, 0.f, 0.f, 0.f};

    STAGEA(0, 0);
    LOADB1(0, 0);

    #pragma unroll
    for (int kt = 0; kt < 16; ++kt) {
        const int p = kt & 1;
        if (kt < 15) {
            STAGEA(kt + 1, p ^ 1);
            LOADB1(kt + 1, p ^ 1);
            VMCNT(8);
        } else {
            VMCNT(0);
        }
        __builtin_amdgcn_s_barrier();
        bf16x8 af[2];
        #pragma unroll
        for (int m = 0; m < 2; ++m) {
            const int row = wr * 32 + m * 16 + lc;
            const char* base = ldsb + p * 16384 + row * 128;
            const f32x4 lo = *(const f32x4*)(base + (((grp * 2) ^ (row & 7)) * 16));
            const f32x4 hi = *(const f32x4*)(base + (((grp * 2 + 1) ^ (row & 7)) * 16));
            bf16x8 v;
            v[0] = (__bf16)lo[0]; v[1] = (__bf16)lo[1]; v[2] = (__bf16)lo[2]; v[3] = (__bf16)lo[3];
            v[4] = (__bf16)hi[0]; v[5] = (__bf16)hi[1]; v[6] = (__bf16)hi[2]; v[7] = (__bf16)hi[3];
            af[m] = v;
        }
        __builtin_amdgcn_s_setprio(1);
        #pragma unroll
        for (int m = 0; m < 2; ++m)
            #pragma unroll
            for (int n = 0; n < 4; ++n)
                acc[m][n] = __builtin_amdgcn_mfma_f32_16x16x32_bf16(af[m], bb[p][n], acc[m][n], 0, 0, 0);
        __builtin_amdgcn_s_setprio(0);
        __builtin_amdgcn_s_barrier();
    }
    #undef STAGEA
    #undef LOADB1

    // ---- softmax (head h) + frag-order repack via wave-private LDS
    float b2v[4];
    #pragma unroll
    for (int n = 0; n < 4; ++n) b2v[n] = b2[h * 64 + n * 16 + lc];

    char* wslab = ldsb + wr * 4096;   // 4 frags x 1024B (wave's 32r x 64c)
    #pragma unroll
    for (int m = 0; m < 2; ++m) {
        const int lr = m * 16 + grp * 4;
        const int4 mv = *(const int4*)(mask + gr0 + wr * 32 + lr);
        const int mk[4] = {mv.x, mv.y, mv.z, mv.w};
        #pragma unroll
        for (int j = 0; j < 4; ++j) {
            float s0 = (acc[m][0][j] + b2v[0]) * 0.125f;
            float s1 = (acc[m][1][j] + b2v[1]) * 0.125f;
            float s2 = (acc[m][2][j] + b2v[2]) * 0.125f;
            float s3 = (acc[m][3][j] + b2v[3]) * 0.125f;
            float mx = fmaxf(fmaxf(s0, s1), fmaxf(s2, s3));
            mx = fmaxf(mx, __shfl_xor(mx, 1));
            mx = fmaxf(mx, __shfl_xor(mx, 2));
            mx = fmaxf(mx, __shfl_xor(mx, 4));
            mx = fmaxf(mx, __shfl_xor(mx, 8));
            float p0 = __expf(s0 - mx);
            float p1 = __expf(s1 - mx);
            float p2 = __expf(s2 - mx);
            float p3 = __expf(s3 - mx);
            float sm = (p0 + p1) + (p2 + p3);
            sm += __shfl_xor(sm, 1);
            sm += __shfl_xor(sm, 2);
            sm += __shfl_xor(sm, 4);
            sm += __shfl_xor(sm, 8);
            float a[4];
            if (mk[j] == 0) {
                a[0] = a[1] = a[2] = a[3] = 0.015625f;  // fp32 -1e9 bias -> uniform attn
            } else {
                const float inv = 1.0f / sm;
                a[0] = p0 * inv; a[1] = p1 * inv; a[2] = p2 * inv; a[3] = p3 * inv;
            }
            #pragma unroll
            for (int n = 0; n < 4; ++n) {
                const int off = (((n >> 1) * 2 + m) << 10)
                              + (((((n & 1) * 2 + (lc >> 3)) << 4) + (grp * 4 + j)) << 4)
                              + ((lc & 7) << 1);
                *(short*)(wslab + off) = (short)bfbits(a[n]);
            }
        }
    }
    // coalesced copy-out: frag-linear global layout (panel = 128 rows = 128KB)
    char* ablk = (char*)attn_p + (size_t)rt * 131072;
    #pragma unroll
    for (int s = 0; s < 2; ++s) {
        #pragma unroll
        for (int m = 0; m < 2; ++m) {
            bf16x8 v = *(const bf16x8*)(wslab + (s * 2 + m) * 1024 + lane * 16);
            *(bf16x8*)(ablk + ((h * 2 + s) * 8 + wr * 2 + m) * 1024 + lane * 16) = v;
        }
    }
}

// ---------------- kernel 2: out = attn@W3 + bo (no LDS, no barriers) ----------
// Block: 128 rows x 64 cols; 4 waves of 32x64. 3-deep reg prefetch.
__global__ __launch_bounds__(256, 4) void k2_gemm_out(
    const __bf16* __restrict__ attn_p, const __bf16* __restrict__ W3fr,
    const float* __restrict__ bo, float* __restrict__ out, int row0) {
    const int tid = threadIdx.x;
    const int lane = tid & 63;
    const int wr = tid >> 6;          // 0..3 = 32-row strip
    const int lc = lane & 15, grp = lane >> 4;
    const int swz = xcd_swz(blockIdx.x, gridDim.x);
    const int nt = swz & 7, rt = swz >> 3;
    const int c0 = nt * 64;

    const char* abase = (const char*)attn_p + (size_t)rt * 131072 + (wr * 2) * 1024 + lane * 16;
    const char* bbase = (const char*)W3fr + (size_t)nt * 65536 + lane * 16;

    #define LA2(kt, buf)                                                           \
        { _Pragma("unroll")                                                        \
          for (int m = 0; m < 2; ++m)                                              \
              aa[buf][m] = *(const bf16x8*)(abase + ((kt) * 8 + m) * 1024); }
    #define LB2(kt, buf)                                                           \
        { _Pragma("unroll")                                                        \
          for (int n = 0; n < 4; ++n)                                              \
              bb[buf][n] = *(const bf16x8*)(bbase + ((kt) * 4 + n) * 1024); }

    bf16x8 aa[3][2], bb[3][4];
    f32x4 acc[2][4];
    #pragma unroll
    for (int m = 0; m < 2; ++m)
        #pragma unroll
        for (int n = 0; n < 4; ++n) acc[m][n] = (f32x4){0.f, 0.f, 0.f, 0.f};

    LA2(0, 0); LB2(0, 0);
    LA2(1, 1); LB2(1, 1);

    #pragma unroll
    for (int kt = 0; kt < 16; ++kt) {
        const int p = kt % 3;
        if (kt < 14) {
            const int q = (kt + 2) % 3;
            LA2(kt + 2, q);
            LB2(kt + 2, q);
        }
        __builtin_amdgcn_s_setprio(1);
        #pragma unroll
        for (int m = 0; m < 2; ++m)
            #pragma unroll
            for (int n = 0; n < 4; ++n)
                acc[m][n] = __builtin_amdgcn_mfma_f32_16x16x32_bf16(aa[p][m], bb[p][n], acc[m][n], 0, 0, 0);
        __builtin_amdgcn_s_setprio(0);
    }
    #undef LA2
    #undef LB2

    float bov[4];
    #pragma unroll
    for (int n = 0; n < 4; ++n) bov[n] = bo[c0 + n * 16 + lc];

    #pragma unroll
    for (int m = 0; m < 2; ++m) {
        #pragma unroll
        for (int j = 0; j < 4; ++j) {
            const int gr = row0 + rt * 128 + wr * 32 + m * 16 + grp * 4 + j;
            float* orow = out + (size_t)gr * DD + c0 + lc;
            #pragma unroll
            for (int n = 0; n < 4; ++n)
                __builtin_nontemporal_store(acc[m][n][j] + bov[n], orow + n * 16);
        }
    }
}

extern "C" void kernel_launch(void* const* d_in, const int* in_sizes, int n_in,
                              void* d_out, int out_size, void* d_ws, size_t ws_size,
                              hipStream_t stream) {
    const float* qf     = (const float*)d_in[0];
    const int*   mask   = (const int*)d_in[1];
    const float* memory = (const float*)d_in[2];
    const float* Wq     = (const float*)d_in[3];
    const float* bq     = (const float*)d_in[4];
    const float* Wk     = (const float*)d_in[5];
    const float* bk     = (const float*)d_in[6];
    const float* Wv     = (const float*)d_in[7];
    const float* bv     = (const float*)d_in[8];
    const float* Wo     = (const float*)d_in[9];
    const float* bo     = (const float*)d_in[10];

    char* ws = (char*)d_ws;
    float*  kproj = (float*)ws;                  // 128 KB
    float*  vproj = (float*)(ws + 131072);       // 128 KB
    float*  b2    = (float*)(ws + 262144);       // 2 KB
    __bf16* W2fr  = (__bf16*)(ws + 264192);      // 512 KB
    __bf16* W3fr  = (__bf16*)(ws + 788480);      // 512 KB
    __bf16* attn_p= (__bf16*)(ws + 1572864);     // frag-order intermediate

    size_t avail = ws_size > 1572864 ? ws_size - 1572864 : 0;
    long mr = (long)(avail / 1024);              // 1024 B per row
    int rpc = (int)((mr / 128) * 128);
    if (rpc > NROWS) rpc = NROWS;
    if (rpc < 128) rpc = 128;

    prep_kv<<<64, 256, 0, stream>>>(memory, Wk, bk, Wv, bv, kproj, vproj);
    prep_w<<<512, 256, 0, stream>>>(Wq, bq, Wo, kproj, vproj, W2fr, b2, W3fr);

    for (int row0 = 0; row0 < NROWS; row0 += rpc) {
        int rows = NROWS - row0; if (rows > rpc) rows = rpc;
        const int nwg = (rows / 128) * 8;
        k1_gemm_sm<<<nwg, 256, 0, stream>>>(qf, mask, W2fr, b2, attn_p, row0);
        k2_gemm_out<<<nwg, 256, 0, stream>>>(attn_p, W3fr, bo, (float*)d_out, row0);
    }
}

// Round 11
// 345.120 us; speedup vs baseline: 1.2417x; 1.2417x over previous
//
#include <hip/hip_runtime.h>
#include <hip/hip_bf16.h>

#define DD 512
#define HDIM 64
#define NROWS 131072

typedef __bf16 bf16x8 __attribute__((ext_vector_type(8)));
typedef float f32x4 __attribute__((ext_vector_type(4)));

static __device__ __forceinline__ unsigned bfbits(float f) {
    union { float f; unsigned u; } x; x.f = f;
    unsigned r = x.u + 0x7fffu + ((x.u >> 16) & 1u);
    return r >> 16;
}
static __device__ __forceinline__ __bf16 to_bf16(float f) {
    union { unsigned short s; __bf16 b; } y; y.s = (unsigned short)bfbits(f); return y.b;
}

// 8 KB step-image: [p 0..127 rows-or-cols][gran 0..3][elem 0..7] bf16.
// 16B-granule XOR swizzle by row: ds_read_b128 frag reads are ~2-way (free).
static __device__ __forceinline__ int img8k(int p, int g, int e) {
    return p * 64 + (((g) ^ ((p) & 3)) << 4) + e * 2;
}

static __device__ __forceinline__ void gll16(const void* gsrc, void* ldst) {
    __builtin_amdgcn_global_load_lds(
        (const __attribute__((address_space(1))) unsigned int*)gsrc,
        (__attribute__((address_space(3))) unsigned int*)ldst, 16, 0, 0);
}

#define VMCNT(n) asm volatile("s_waitcnt vmcnt(" #n ")" ::: "memory")
#define VM_LGKM(n) asm volatile("s_waitcnt vmcnt(" #n ") lgkmcnt(0)" ::: "memory")

// bijective XCD-chunk swizzle (m204)
static __device__ __forceinline__ int xcd_swz(int bid, int nwg) {
    const int q = nwg >> 3, r = nwg & 7;
    const int xcd = bid & 7, idx = bid >> 3;
    return (xcd < r ? xcd * (q + 1) : r * (q + 1) + (xcd - r) * q) + idx;
}

// ---------------- prep 1: k/v projections of memory (tiny) ----------------
__global__ void prep_kv(const float* __restrict__ memory,
                        const float* __restrict__ Wk, const float* __restrict__ bk,
                        const float* __restrict__ Wv, const float* __restrict__ bv,
                        float* __restrict__ kproj, float* __restrict__ vproj) {
    __shared__ float mrow[DD];
    const int m = blockIdx.x;
    const int t = threadIdx.x;
    for (int i = t; i < DD; i += 256) mrow[i] = memory[(size_t)m * DD + i];
    __syncthreads();
    for (int jj = 0; jj < 2; ++jj) {
        const int j = t + jj * 256;
        const float* wkr = Wk + (size_t)j * DD;
        const float* wvr = Wv + (size_t)j * DD;
        float sk = 0.f, sv = 0.f;
        for (int d = 0; d < DD; ++d) {
            const float md = mrow[d];
            sk += md * wkr[d];
            sv += md * wvr[d];
        }
        kproj[(size_t)m * DD + j] = sk + bk[j];
        vproj[(size_t)m * DD + j] = sv + bv[j];
    }
}

// ---------------- prep 2: fold into W2img / b2 / W3img (step-image layout) ----
// W2img: [nt = c>>7][step = d>>5] image of (col c&127, k-dim d).
// W3img: [nt = j>>7][step = c>>5] image of (col j&127, k-dim c).
__global__ void prep_w(const float* __restrict__ Wq, const float* __restrict__ bq,
                       const float* __restrict__ Wo,
                       const float* __restrict__ kproj, const float* __restrict__ vproj,
                       char* __restrict__ W2img, float* __restrict__ b2,
                       char* __restrict__ W3img) {
    const int i = blockIdx.x;   // c (score-col) for W2img/b2; j (out-col) for W3img
    const int t = threadIdx.x;
    __shared__ float kp[HDIM];
    __shared__ float worow[DD];
    const int m = i & 63, h = i >> 6;
    if (t < HDIM) kp[t] = kproj[(size_t)m * DD + h * HDIM + t];
    for (int d = t; d < DD; d += 256) worow[d] = Wo[(size_t)i * DD + d];
    __syncthreads();
    for (int dd2 = 0; dd2 < 2; ++dd2) {
        const int d = t + dd2 * 256;
        float s = 0.f;
        #pragma unroll 8
        for (int hd = 0; hd < HDIM; ++hd)
            s += Wq[(size_t)(h * HDIM + hd) * DD + d] * kp[hd];
        *(__bf16*)(W2img + (size_t)((i >> 7) * 16 + (d >> 5)) * 8192
                   + img8k(i & 127, (d >> 3) & 3, d & 7)) = to_bf16(s);
    }
    if (t == 0) {
        float s = 0.f;
        for (int hd = 0; hd < HDIM; ++hd) s += bq[h * HDIM + hd] * kp[hd];
        b2[i] = s;
    }
    for (int cc = 0; cc < 2; ++cc) {
        const int c = t + cc * 256;
        const int mc = c & 63, hc = c >> 6;
        float s = 0.f;
        #pragma unroll 8
        for (int hd = 0; hd < HDIM; ++hd)
            s += vproj[(size_t)mc * DD + hc * HDIM + hd] * worow[hc * HDIM + hd];
        *(__bf16*)(W3img + (size_t)((i >> 7) * 16 + (c >> 5)) * 8192
                   + img8k(i & 127, (c >> 3) & 3, c & 7)) = to_bf16(s);
    }
}

// ---------------- kernel 1: S = x@W2 + b2, softmax -> attn step-images --------
// 128x128 tile, BK=32, 16 K-steps. 4 waves (2x2), wave = 64x64, acc[4][4].
// A: fp32 global -> regs (2 steps ahead) -> cvt -> ds_write bf16 image.
// B: gll from pre-swizzled W2img. One raw barrier/step, counted vmcnt.
__global__ __launch_bounds__(256, 3) void k1_gemm_sm(
    const float* __restrict__ x, const int* __restrict__ mask,
    const char* __restrict__ W2img, const float* __restrict__ b2,
    char* __restrict__ attn_p, int row0) {
    __shared__ char ldsb[32768];   // A: 0/8192, B: 16384/24576

    const int tid = threadIdx.x;
    const int lane = tid & 63;
    const int wid = tid >> 6;
    const int wm = wid >> 1, wn = wid & 1;
    const int lc = lane & 15, grp = lane >> 4;
    const int swz = xcd_swz(blockIdx.x, gridDim.x);
    const int nt = swz & 3, rt = swz >> 2;
    const int gr0 = row0 + rt * 128;
    const int h = nt * 2 + wn;
    const int aswz = (grp ^ (lc & 3)) << 4;

    const char* bsrc = W2img + (size_t)nt * 16 * 8192 + wid * 2048 + lane * 16;

    // A-staging: thread slots i=0,1; slot = i*256+tid -> (row, granule)
    const float* asrc[2]; int adst[2];
    #pragma unroll
    for (int i = 0; i < 2; ++i) {
        const int slot = i * 256 + tid;
        const int r = slot >> 2, g = slot & 3;
        asrc[i] = x + (size_t)(gr0 + r) * DD + g * 8;
        adst[i] = img8k(r, g, 0);
    }

    f32x4 sreg[2][4];
    #define ALOAD(kt, set)                                                         \
        { _Pragma("unroll")                                                        \
          for (int i = 0; i < 2; ++i) {                                            \
              sreg[set][i*2]   = *(const f32x4*)(asrc[i] + (kt) * 32);             \
              sreg[set][i*2+1] = *(const f32x4*)(asrc[i] + (kt) * 32 + 4);         \
          } }
    #define AWRITE(buf, set)                                                       \
        { _Pragma("unroll")                                                        \
          for (int i = 0; i < 2; ++i) {                                            \
              uint4 u;                                                             \
              u.x = bfbits(sreg[set][i*2][0])   | (bfbits(sreg[set][i*2][1]) << 16);   \
              u.y = bfbits(sreg[set][i*2][2])   | (bfbits(sreg[set][i*2][3]) << 16);   \
              u.z = bfbits(sreg[set][i*2+1][0]) | (bfbits(sreg[set][i*2+1][1]) << 16); \
              u.w = bfbits(sreg[set][i*2+1][2]) | (bfbits(sreg[set][i*2+1][3]) << 16); \
              *(uint4*)(ldsb + (buf) * 8192 + adst[i]) = u;                        \
          } }
    #define BGLL(kt, buf)                                                          \
        { gll16(bsrc + (size_t)(kt) * 8192,        ldsb + 16384 + (buf) * 8192 + wid * 2048);        \
          gll16(bsrc + (size_t)(kt) * 8192 + 1024, ldsb + 16384 + (buf) * 8192 + wid * 2048 + 1024); }
    #define LDA1(p, m) (*(const bf16x8*)(ldsb + (p) * 8192 + (wm * 64 + (m) * 16 + lc) * 64 + aswz))
    #define LDB1(p, n) (*(const bf16x8*)(ldsb + 16384 + (p) * 8192 + (wn * 64 + (n) * 16 + lc) * 64 + aswz))

    f32x4 acc[4][4];
    #pragma unroll
    for (int m = 0; m < 4; ++m)
        #pragma unroll
        for (int n = 0; n < 4; ++n) acc[m][n] = (f32x4){0.f, 0.f, 0.f, 0.f};

    // prologue: B(0) gll, A(0)/A(1) loads; wait gll0+A0; write A0; barrier
    BGLL(0, 0);
    ALOAD(0, 0);
    ALOAD(1, 1);
    VMCNT(4);
    AWRITE(0, 0);
    asm volatile("s_waitcnt lgkmcnt(0)" ::: "memory");
    __builtin_amdgcn_s_barrier();

    #pragma unroll
    for (int s = 0; s < 16; ++s) {
        const int p = s & 1;
        if (s < 15) BGLL(s + 1, p ^ 1);          // +2 gll
        if (s < 14) ALOAD(s + 2, s & 1);         // +4 loads (2 steps ahead)
        bf16x8 af[4], bf[4];
        #pragma unroll
        for (int m = 0; m < 4; ++m) af[m] = LDA1(p, m);
        #pragma unroll
        for (int n = 0; n < 4; ++n) bf[n] = LDB1(p, n);
        __builtin_amdgcn_s_setprio(1);
        #pragma unroll
        for (int m = 0; m < 4; ++m)
            #pragma unroll
            for (int n = 0; n < 4; ++n)
                acc[m][n] = __builtin_amdgcn_mfma_f32_16x16x32_bf16(af[m], bf[n], acc[m][n], 0, 0, 0);
        __builtin_amdgcn_s_setprio(0);
        if (s < 14)      { VMCNT(6); AWRITE(p ^ 1, (s + 1) & 1); VM_LGKM(4); __builtin_amdgcn_s_barrier(); }
        else if (s < 15) { VMCNT(2); AWRITE(p ^ 1, (s + 1) & 1); VM_LGKM(0); __builtin_amdgcn_s_barrier(); }
    }
    #undef ALOAD
    #undef AWRITE
    #undef BGLL
    #undef LDA1
    #undef LDB1
    __syncthreads();   // all frag reads done -> LDS reusable for repack

    // ---- softmax (wave-local head h) + image repack via wave-private LDS slab
    float b2v[4];
    #pragma unroll
    for (int n = 0; n < 4; ++n) b2v[n] = b2[h * 64 + n * 16 + lc];

    char* wslab = ldsb + wid * 8192;   // 2 sub-steps x 4KB (64 rows x 32 k)
    #pragma unroll
    for (int m = 0; m < 4; ++m) {
        const int lr = m * 16 + grp * 4;
        const int4 mv = *(const int4*)(mask + gr0 + wm * 64 + lr);
        const int mk[4] = {mv.x, mv.y, mv.z, mv.w};
        #pragma unroll
        for (int j = 0; j < 4; ++j) {
            float s0 = (acc[m][0][j] + b2v[0]) * 0.125f;
            float s1 = (acc[m][1][j] + b2v[1]) * 0.125f;
            float s2 = (acc[m][2][j] + b2v[2]) * 0.125f;
            float s3 = (acc[m][3][j] + b2v[3]) * 0.125f;
            float mx = fmaxf(fmaxf(s0, s1), fmaxf(s2, s3));
            mx = fmaxf(mx, __shfl_xor(mx, 1));
            mx = fmaxf(mx, __shfl_xor(mx, 2));
            mx = fmaxf(mx, __shfl_xor(mx, 4));
            mx = fmaxf(mx, __shfl_xor(mx, 8));
            float p0 = __expf(s0 - mx);
            float p1 = __expf(s1 - mx);
            float p2 = __expf(s2 - mx);
            float p3 = __expf(s3 - mx);
            float sm = (p0 + p1) + (p2 + p3);
            sm += __shfl_xor(sm, 1);
            sm += __shfl_xor(sm, 2);
            sm += __shfl_xor(sm, 4);
            sm += __shfl_xor(sm, 8);
            float a[4];
            if (mk[j] == 0) {
                a[0] = a[1] = a[2] = a[3] = 0.015625f;   // fp32 -1e9 bias -> uniform attn
            } else {
                const float inv = 1.0f / sm;
                a[0] = p0 * inv; a[1] = p1 * inv; a[2] = p2 * inv; a[3] = p3 * inv;
            }
            const int rl = lr + j;
            #pragma unroll
            for (int n = 0; n < 4; ++n) {
                const int gqn = (((n & 1) << 1) | (lc >> 3));
                const int off = (n >> 1) * 4096 + rl * 64 + ((gqn ^ (rl & 3)) << 4) + ((lc & 7) << 1);
                *(short*)(wslab + off) = (short)bfbits(a[n]);
            }
        }
    }
    // coalesced copy-out into attn step-images (steps 2h, 2h+1; rows wm*64..+63)
    char* ablk = attn_p + (size_t)rt * 131072 + (size_t)(2 * h) * 8192 + wm * 4096;
    #pragma unroll
    for (int st = 0; st < 2; ++st) {
        #pragma unroll
        for (int i = 0; i < 4; ++i) {
            bf16x8 v = *(const bf16x8*)(wslab + st * 4096 + i * 1024 + lane * 16);
            *(bf16x8*)(ablk + st * 8192 + i * 1024 + lane * 16) = v;
        }
    }
}

// ---------------- kernel 2: out = attn@W3 + bo --------------------------------
// 128x128 tile, BK=32. Triple-buffered LDS, 2-step-deep gll for A and B.
__global__ __launch_bounds__(256, 3) void k2_gemm_out(
    const char* __restrict__ attn_p, const char* __restrict__ W3img,
    const float* __restrict__ bo, float* __restrict__ out, int row0) {
    __shared__ char ldsb[49152];   // buf b: A @ b*16384, B @ b*16384+8192

    const int tid = threadIdx.x;
    const int lane = tid & 63;
    const int wid = tid >> 6;
    const int wm = wid >> 1, wn = wid & 1;
    const int lc = lane & 15, grp = lane >> 4;
    const int swz = xcd_swz(blockIdx.x, gridDim.x);
    const int nt = swz & 3, rt = swz >> 2;
    const int c0 = nt * 128 + wn * 64;
    const int aswz = (grp ^ (lc & 3)) << 4;

    const char* asrc = attn_p + (size_t)rt * 131072 + wid * 2048 + lane * 16;
    const char* bsrc = W3img + (size_t)nt * 16 * 8192 + wid * 2048 + lane * 16;

    #define STG2(kt, b)                                                            \
        { gll16(asrc + (size_t)(kt) * 8192,        ldsb + (b) * 16384 + wid * 2048);               \
          gll16(asrc + (size_t)(kt) * 8192 + 1024, ldsb + (b) * 16384 + wid * 2048 + 1024);        \
          gll16(bsrc + (size_t)(kt) * 8192,        ldsb + (b) * 16384 + 8192 + wid * 2048);        \
          gll16(bsrc + (size_t)(kt) * 8192 + 1024, ldsb + (b) * 16384 + 8192 + wid * 2048 + 1024); }
    #define LDA2(b, m) (*(const bf16x8*)(ldsb + (b) * 16384 + (wm * 64 + (m) * 16 + lc) * 64 + aswz))
    #define LDB2(b, n) (*(const bf16x8*)(ldsb + (b) * 16384 + 8192 + (wn * 64 + (n) * 16 + lc) * 64 + aswz))

    f32x4 acc[4][4];
    #pragma unroll
    for (int m = 0; m < 4; ++m)
        #pragma unroll
        for (int n = 0; n < 4; ++n) acc[m][n] = (f32x4){0.f, 0.f, 0.f, 0.f};

    STG2(0, 0);
    STG2(1, 1);
    VMCNT(4);
    __builtin_amdgcn_s_barrier();

    #pragma unroll
    for (int s = 0; s < 16; ++s) {
        const int b = s % 3;
        if (s < 14) STG2(s + 2, (s + 2) % 3);
        bf16x8 af[4], bf[4];
        #pragma unroll
        for (int m = 0; m < 4; ++m) af[m] = LDA2(b, m);
        #pragma unroll
        for (int n = 0; n < 4; ++n) bf[n] = LDB2(b, n);
        __builtin_amdgcn_s_setprio(1);
        #pragma unroll
        for (int m = 0; m < 4; ++m)
            #pragma unroll
            for (int n = 0; n < 4; ++n)
                acc[m][n] = __builtin_amdgcn_mfma_f32_16x16x32_bf16(af[m], bf[n], acc[m][n], 0, 0, 0);
        __builtin_amdgcn_s_setprio(0);
        if (s < 14)      { VMCNT(4); __builtin_amdgcn_s_barrier(); }
        else if (s < 15) { VMCNT(0); __builtin_amdgcn_s_barrier(); }
    }
    #undef STG2
    #undef LDA2
    #undef LDB2

    float bov[4];
    #pragma unroll
    for (int n = 0; n < 4; ++n) bov[n] = bo[c0 + n * 16 + lc];

    #pragma unroll
    for (int m = 0; m < 4; ++m) {
        #pragma unroll
        for (int j = 0; j < 4; ++j) {
            const int gr = row0 + rt * 128 + wm * 64 + m * 16 + grp * 4 + j;
            float* orow = out + (size_t)gr * DD + c0 + lc;
            #pragma unroll
            for (int n = 0; n < 4; ++n)
                __builtin_nontemporal_store(acc[m][n][j] + bov[n], orow + n * 16);
        }
    }
}

extern "C" void kernel_launch(void* const* d_in, const int* in_sizes, int n_in,
                              void* d_out, int out_size, void* d_ws, size_t ws_size,
                              hipStream_t stream) {
    const float* qf     = (const float*)d_in[0];
    const int*   mask   = (const int*)d_in[1];
    const float* memory = (const float*)d_in[2];
    const float* Wq     = (const float*)d_in[3];
    const float* bq     = (const float*)d_in[4];
    const float* Wk     = (const float*)d_in[5];
    const float* bk     = (const float*)d_in[6];
    const float* Wv     = (const float*)d_in[7];
    const float* bv     = (const float*)d_in[8];
    const float* Wo     = (const float*)d_in[9];
    const float* bo     = (const float*)d_in[10];

    char* ws = (char*)d_ws;
    float* kproj  = (float*)ws;                  // 128 KB
    float* vproj  = (float*)(ws + 131072);       // 128 KB
    float* b2     = (float*)(ws + 262144);       // 2 KB
    char*  W2img  = ws + 264192;                 // 512 KB
    char*  W3img  = ws + 788480;                 // 512 KB
    char*  attn_p = ws + 1572864;                // step-image intermediate

    size_t avail = ws_size > 1572864 ? ws_size - 1572864 : 0;
    long mr = (long)(avail / 1024);              // 1 KB per row
    int rpc = (int)((mr / 128) * 128);
    if (rpc > NROWS) rpc = NROWS;
    if (rpc < 128) rpc = 128;

    prep_kv<<<64, 256, 0, stream>>>(memory, Wk, bk, Wv, bv, kproj, vproj);
    prep_w<<<512, 256, 0, stream>>>(Wq, bq, Wo, kproj, vproj, W2img, b2, W3img);

    for (int row0 = 0; row0 < NROWS; row0 += rpc) {
        int rows = NROWS - row0; if (rows > rpc) rows = rpc;
        const int nwg = (rows / 128) * 4;
        k1_gemm_sm<<<nwg, 256, 0, stream>>>(qf, mask, W2img, b2, attn_p, row0);
        k2_gemm_out<<<nwg, 256, 0, stream>>>(attn_p, W3img, bo, (float*)d_out, row0);
    }
}

// Round 12
// 342.179 us; speedup vs baseline: 1.2523x; 1.0086x over previous
//
#include <hip/hip_runtime.h>
#include <hip/hip_bf16.h>

#define DD 512
#define HDIM 64
#define NROWS 131072

typedef __bf16 bf16x8 __attribute__((ext_vector_type(8)));
typedef float f32x4 __attribute__((ext_vector_type(4)));

static __device__ __forceinline__ unsigned bfbits(float f) {
    union { float f; unsigned u; } x; x.f = f;
    unsigned r = x.u + 0x7fffu + ((x.u >> 16) & 1u);
    return r >> 16;
}
static __device__ __forceinline__ __bf16 to_bf16(float f) {
    union { unsigned short s; __bf16 b; } y; y.s = (unsigned short)bfbits(f); return y.b;
}

// 8 KB step-image: [p 0..127 rows-or-cols][gran 0..3][elem 0..7] bf16.
// Double-XOR granule swizzle: lanes 1-apart AND 4-apart land on distinct
// granules -> ds_read_b128 frag reads are 2-way (free per m136).
static __device__ __forceinline__ int img8k(int p, int g, int e) {
    return p * 64 + ((((g) ^ ((p) & 3) ^ (((p) >> 2) & 3)) & 3) << 4) + e * 2;
}

static __device__ __forceinline__ void gll16(const void* gsrc, void* ldst) {
    __builtin_amdgcn_global_load_lds(
        (const __attribute__((address_space(1))) unsigned int*)gsrc,
        (__attribute__((address_space(3))) unsigned int*)ldst, 16, 0, 0);
}

#define VMCNT(n) asm volatile("s_waitcnt vmcnt(" #n ")" ::: "memory")
#define LGKM0 asm volatile("s_waitcnt lgkmcnt(0)" ::: "memory")

// bijective XCD-chunk swizzle (m204)
static __device__ __forceinline__ int xcd_swz(int bid, int nwg) {
    const int q = nwg >> 3, r = nwg & 7;
    const int xcd = bid & 7, idx = bid >> 3;
    return (xcd < r ? xcd * (q + 1) : r * (q + 1) + (xcd - r) * q) + idx;
}

// ---------------- prep 1: k/v projections of memory (tiny) ----------------
__global__ void prep_kv(const float* __restrict__ memory,
                        const float* __restrict__ Wk, const float* __restrict__ bk,
                        const float* __restrict__ Wv, const float* __restrict__ bv,
                        float* __restrict__ kproj, float* __restrict__ vproj) {
    __shared__ float mrow[DD];
    const int m = blockIdx.x;
    const int t = threadIdx.x;
    for (int i = t; i < DD; i += 256) mrow[i] = memory[(size_t)m * DD + i];
    __syncthreads();
    for (int jj = 0; jj < 2; ++jj) {
        const int j = t + jj * 256;
        const float* wkr = Wk + (size_t)j * DD;
        const float* wvr = Wv + (size_t)j * DD;
        float sk = 0.f, sv = 0.f;
        for (int d = 0; d < DD; ++d) {
            const float md = mrow[d];
            sk += md * wkr[d];
            sv += md * wvr[d];
        }
        kproj[(size_t)m * DD + j] = sk + bk[j];
        vproj[(size_t)m * DD + j] = sv + bv[j];
    }
}

// ---------------- prep 2: fold into W2img / b2 / W3img (step-image layout) ----
__global__ void prep_w(const float* __restrict__ Wq, const float* __restrict__ bq,
                       const float* __restrict__ Wo,
                       const float* __restrict__ kproj, const float* __restrict__ vproj,
                       char* __restrict__ W2img, float* __restrict__ b2,
                       char* __restrict__ W3img) {
    const int i = blockIdx.x;   // c (score-col) for W2img/b2; j (out-col) for W3img
    const int t = threadIdx.x;
    __shared__ float kp[HDIM];
    __shared__ float worow[DD];
    const int m = i & 63, h = i >> 6;
    if (t < HDIM) kp[t] = kproj[(size_t)m * DD + h * HDIM + t];
    for (int d = t; d < DD; d += 256) worow[d] = Wo[(size_t)i * DD + d];
    __syncthreads();
    for (int dd2 = 0; dd2 < 2; ++dd2) {
        const int d = t + dd2 * 256;
        float s = 0.f;
        #pragma unroll 8
        for (int hd = 0; hd < HDIM; ++hd)
            s += Wq[(size_t)(h * HDIM + hd) * DD + d] * kp[hd];
        *(__bf16*)(W2img + (size_t)((i >> 7) * 16 + (d >> 5)) * 8192
                   + img8k(i & 127, (d >> 3) & 3, d & 7)) = to_bf16(s);
    }
    if (t == 0) {
        float s = 0.f;
        for (int hd = 0; hd < HDIM; ++hd) s += bq[h * HDIM + hd] * kp[hd];
        b2[i] = s;
    }
    for (int cc = 0; cc < 2; ++cc) {
        const int c = t + cc * 256;
        const int mc = c & 63, hc = c >> 6;
        float s = 0.f;
        #pragma unroll 8
        for (int hd = 0; hd < HDIM; ++hd)
            s += vproj[(size_t)mc * DD + hc * HDIM + hd] * worow[hc * HDIM + hd];
        *(__bf16*)(W3img + (size_t)((i >> 7) * 16 + (c >> 5)) * 8192
                   + img8k(i & 127, (c >> 3) & 3, c & 7)) = to_bf16(s);
    }
}

// ---------------- kernel 1: S = x@W2 + b2, softmax -> attn step-images --------
// 128x128 tile, BK=32, 16 K-steps. 4 waves (2x2), wave = 64x64, acc[4][4].
// A: fp32 global -> regs (2 ahead) -> cvt -> ds_write bf16 image (2 bufs).
// B: gll 2 steps ahead into 3 bufs. One barrier/step; loop vmcnt only on
// loads with >=1-step slack (never drains same-step issues).
__global__ __launch_bounds__(256, 3) void k1_gemm_sm(
    const float* __restrict__ x, const int* __restrict__ mask,
    const char* __restrict__ W2img, const float* __restrict__ b2,
    char* __restrict__ attn_p, int row0) {
    __shared__ char ldsb[40960];   // A: 0/8192 ; B: 16384 + b*8192 (b=0..2)

    const int tid = threadIdx.x;
    const int lane = tid & 63;
    const int wid = tid >> 6;
    const int wm = wid >> 1, wn = wid & 1;
    const int lc = lane & 15, grp = lane >> 4;
    const int swz = xcd_swz(blockIdx.x, gridDim.x);
    const int nt = swz & 3, rt = swz >> 2;
    const int gr0 = row0 + rt * 128;
    const int h = nt * 2 + wn;
    const int aswz = ((grp ^ (lc & 3) ^ (lc >> 2)) & 3) << 4;

    const char* bsrc = W2img + (size_t)nt * 16 * 8192 + wid * 2048 + lane * 16;

    // A-staging: thread slots i=0,1; slot = i*256+tid -> (row, granule)
    const float* asrc[2]; int adst[2];
    #pragma unroll
    for (int i = 0; i < 2; ++i) {
        const int slot = i * 256 + tid;
        const int r = slot >> 2, g = slot & 3;
        asrc[i] = x + (size_t)(gr0 + r) * DD + g * 8;
        adst[i] = img8k(r, g, 0);
    }

    f32x4 sreg[2][4];
    #define ALOAD(kt, set)                                                         \
        { _Pragma("unroll")                                                        \
          for (int i = 0; i < 2; ++i) {                                            \
              sreg[set][i*2]   = *(const f32x4*)(asrc[i] + (kt) * 32);             \
              sreg[set][i*2+1] = *(const f32x4*)(asrc[i] + (kt) * 32 + 4);         \
          } }
    #define AWRITE(buf, set)                                                       \
        { _Pragma("unroll")                                                        \
          for (int i = 0; i < 2; ++i) {                                            \
              uint4 u;                                                             \
              u.x = bfbits(sreg[set][i*2][0])   | (bfbits(sreg[set][i*2][1]) << 16);   \
              u.y = bfbits(sreg[set][i*2][2])   | (bfbits(sreg[set][i*2][3]) << 16);   \
              u.z = bfbits(sreg[set][i*2+1][0]) | (bfbits(sreg[set][i*2+1][1]) << 16); \
              u.w = bfbits(sreg[set][i*2+1][2]) | (bfbits(sreg[set][i*2+1][3]) << 16); \
              *(uint4*)(ldsb + (buf) * 8192 + adst[i]) = u;                        \
          } }
    #define BGLL(kt, buf)                                                          \
        { gll16(bsrc + (size_t)(kt) * 8192,        ldsb + 16384 + (buf) * 8192 + wid * 2048);        \
          gll16(bsrc + (size_t)(kt) * 8192 + 1024, ldsb + 16384 + (buf) * 8192 + wid * 2048 + 1024); }
    #define LDA1(p, m) (*(const bf16x8*)(ldsb + (p) * 8192 + (wm * 64 + (m) * 16 + lc) * 64 + aswz))
    #define LDB1(b, n) (*(const bf16x8*)(ldsb + 16384 + (b) * 8192 + (wn * 64 + (n) * 16 + lc) * 64 + aswz))

    f32x4 acc[4][4];
    #pragma unroll
    for (int m = 0; m < 4; ++m)
        #pragma unroll
        for (int n = 0; n < 4; ++n) acc[m][n] = (f32x4){0.f, 0.f, 0.f, 0.f};

    // prologue: B(0),A(0),B(1),A(1) in flight; wait B0+A0; write A0; barrier.
    BGLL(0, 0);
    ALOAD(0, 0);
    BGLL(1, 1);
    ALOAD(1, 1);
    VMCNT(6);                      // leaves B1(2)+A1(4); B0,A0 done
    AWRITE(0, 0);
    LGKM0;
    __builtin_amdgcn_s_barrier();  // invariant: 6 outstanding = {B(s+1), A(s+1)}

    #pragma unroll
    for (int s = 0; s < 16; ++s) {
        const int ab = s & 1, bb = s % 3;
        if (s < 14) {
            BGLL(s + 2, (s + 2) % 3);   // +2
            ALOAD(s + 2, s & 1);        // +4 (sreg s&1 freed by AWRITE(s) last step)
        }
        bf16x8 af[4], bf[4];
        #pragma unroll
        for (int m = 0; m < 4; ++m) af[m] = LDA1(ab, m);
        #pragma unroll
        for (int n = 0; n < 4; ++n) bf[n] = LDB1(bb, n);
        __builtin_amdgcn_s_setprio(1);
        #pragma unroll
        for (int m = 0; m < 4; ++m)
            #pragma unroll
            for (int n = 0; n < 4; ++n)
                acc[m][n] = __builtin_amdgcn_mfma_f32_16x16x32_bf16(af[m], bf[n], acc[m][n], 0, 0, 0);
        __builtin_amdgcn_s_setprio(0);
        if (s < 14) {
            VMCNT(6);                        // waits B(s+1),A(s+1) (issued step s-1)
            AWRITE((s + 1) & 1, (s + 1) & 1);
            LGKM0;
            __builtin_amdgcn_s_barrier();
        } else if (s < 15) {
            VMCNT(0);                        // tail: drain B(15),A(15)
            AWRITE((s + 1) & 1, (s + 1) & 1);
            LGKM0;
            __builtin_amdgcn_s_barrier();
        }
    }
    #undef ALOAD
    #undef AWRITE
    #undef BGLL
    #undef LDA1
    #undef LDB1
    __syncthreads();   // all frag reads done -> LDS reusable for repack

    // ---- softmax (wave-local head h) + image repack via wave-private LDS slab
    float b2v[4];
    #pragma unroll
    for (int n = 0; n < 4; ++n) b2v[n] = b2[h * 64 + n * 16 + lc];

    char* wslab = ldsb + wid * 8192;   // 2 sub-steps x 4KB (64 rows x 32 k)
    #pragma unroll
    for (int m = 0; m < 4; ++m) {
        const int lr = m * 16 + grp * 4;
        const int4 mv = *(const int4*)(mask + gr0 + wm * 64 + lr);
        const int mk[4] = {mv.x, mv.y, mv.z, mv.w};
        #pragma unroll
        for (int j = 0; j < 4; ++j) {
            float s0 = (acc[m][0][j] + b2v[0]) * 0.125f;
            float s1 = (acc[m][1][j] + b2v[1]) * 0.125f;
            float s2 = (acc[m][2][j] + b2v[2]) * 0.125f;
            float s3 = (acc[m][3][j] + b2v[3]) * 0.125f;
            float mx = fmaxf(fmaxf(s0, s1), fmaxf(s2, s3));
            mx = fmaxf(mx, __shfl_xor(mx, 1));
            mx = fmaxf(mx, __shfl_xor(mx, 2));
            mx = fmaxf(mx, __shfl_xor(mx, 4));
            mx = fmaxf(mx, __shfl_xor(mx, 8));
            float p0 = __expf(s0 - mx);
            float p1 = __expf(s1 - mx);
            float p2 = __expf(s2 - mx);
            float p3 = __expf(s3 - mx);
            float sm = (p0 + p1) + (p2 + p3);
            sm += __shfl_xor(sm, 1);
            sm += __shfl_xor(sm, 2);
            sm += __shfl_xor(sm, 4);
            sm += __shfl_xor(sm, 8);
            float a[4];
            if (mk[j] == 0) {
                a[0] = a[1] = a[2] = a[3] = 0.015625f;   // fp32 -1e9 bias -> uniform attn
            } else {
                const float inv = 1.0f / sm;
                a[0] = p0 * inv; a[1] = p1 * inv; a[2] = p2 * inv; a[3] = p3 * inv;
            }
            const int rl = lr + j;
            #pragma unroll
            for (int n = 0; n < 4; ++n) {
                const int gqn = (((n & 1) << 1) | (lc >> 3));
                const int gsw = (gqn ^ (rl & 3) ^ ((rl >> 2) & 3)) & 3;
                const int off = (n >> 1) * 4096 + rl * 64 + (gsw << 4) + ((lc & 7) << 1);
                *(short*)(wslab + off) = (short)bfbits(a[n]);
            }
        }
    }
    // coalesced copy-out into attn step-images (steps 2h, 2h+1; rows wm*64..+63)
    char* ablk = attn_p + (size_t)rt * 131072 + (size_t)(2 * h) * 8192 + wm * 4096;
    #pragma unroll
    for (int st = 0; st < 2; ++st) {
        #pragma unroll
        for (int i = 0; i < 4; ++i) {
            bf16x8 v = *(const bf16x8*)(wslab + st * 4096 + i * 1024 + lane * 16);
            *(bf16x8*)(ablk + st * 8192 + i * 1024 + lane * 16) = v;
        }
    }
}

// ---------------- kernel 2: out = attn@W3 + bo --------------------------------
// 128x128 tile, BK=32. Triple-buffered LDS, 2-step-deep gll for A and B.
__global__ __launch_bounds__(256, 3) void k2_gemm_out(
    const char* __restrict__ attn_p, const char* __restrict__ W3img,
    const float* __restrict__ bo, float* __restrict__ out, int row0) {
    __shared__ char ldsb[49152];   // buf b: A @ b*16384, B @ b*16384+8192

    const int tid = threadIdx.x;
    const int lane = tid & 63;
    const int wid = tid >> 6;
    const int wm = wid >> 1, wn = wid & 1;
    const int lc = lane & 15, grp = lane >> 4;
    const int swz = xcd_swz(blockIdx.x, gridDim.x);
    const int nt = swz & 3, rt = swz >> 2;
    const int c0 = nt * 128 + wn * 64;
    const int aswz = ((grp ^ (lc & 3) ^ (lc >> 2)) & 3) << 4;

    const char* asrc = attn_p + (size_t)rt * 131072 + wid * 2048 + lane * 16;
    const char* bsrc = W3img + (size_t)nt * 16 * 8192 + wid * 2048 + lane * 16;

    #define STG2(kt, b)                                                            \
        { gll16(asrc + (size_t)(kt) * 8192,        ldsb + (b) * 16384 + wid * 2048);               \
          gll16(asrc + (size_t)(kt) * 8192 + 1024, ldsb + (b) * 16384 + wid * 2048 + 1024);        \
          gll16(bsrc + (size_t)(kt) * 8192,        ldsb + (b) * 16384 + 8192 + wid * 2048);        \
          gll16(bsrc + (size_t)(kt) * 8192 + 1024, ldsb + (b) * 16384 + 8192 + wid * 2048 + 1024); }
    #define LDA2(b, m) (*(const bf16x8*)(ldsb + (b) * 16384 + (wm * 64 + (m) * 16 + lc) * 64 + aswz))
    #define LDB2(b, n) (*(const bf16x8*)(ldsb + (b) * 16384 + 8192 + (wn * 64 + (n) * 16 + lc) * 64 + aswz))

    f32x4 acc[4][4];
    #pragma unroll
    for (int m = 0; m < 4; ++m)
        #pragma unroll
        for (int n = 0; n < 4; ++n) acc[m][n] = (f32x4){0.f, 0.f, 0.f, 0.f};

    STG2(0, 0);
    STG2(1, 1);
    VMCNT(4);
    __builtin_amdgcn_s_barrier();

    #pragma unroll
    for (int s = 0; s < 16; ++s) {
        const int b = s % 3;
        if (s < 14) STG2(s + 2, (s + 2) % 3);
        bf16x8 af[4], bf[4];
        #pragma unroll
        for (int m = 0; m < 4; ++m) af[m] = LDA2(b, m);
        #pragma unroll
        for (int n = 0; n < 4; ++n) bf[n] = LDB2(b, n);
        __builtin_amdgcn_s_setprio(1);
        #pragma unroll
        for (int m = 0; m < 4; ++m)
            #pragma unroll
            for (int n = 0; n < 4; ++n)
                acc[m][n] = __builtin_amdgcn_mfma_f32_16x16x32_bf16(af[m], bf[n], acc[m][n], 0, 0, 0);
        __builtin_amdgcn_s_setprio(0);
        if (s < 14)      { VMCNT(4); __builtin_amdgcn_s_barrier(); }
        else if (s < 15) { VMCNT(0); __builtin_amdgcn_s_barrier(); }
    }
    #undef STG2
    #undef LDA2
    #undef LDB2

    float bov[4];
    #pragma unroll
    for (int n = 0; n < 4; ++n) bov[n] = bo[c0 + n * 16 + lc];

    #pragma unroll
    for (int m = 0; m < 4; ++m) {
        #pragma unroll
        for (int j = 0; j < 4; ++j) {
            const int gr = row0 + rt * 128 + wm * 64 + m * 16 + grp * 4 + j;
            float* orow = out + (size_t)gr * DD + c0 + lc;
            #pragma unroll
            for (int n = 0; n < 4; ++n)
                __builtin_nontemporal_store(acc[m][n][j] + bov[n], orow + n * 16);
        }
    }
}

extern "C" void kernel_launch(void* const* d_in, const int* in_sizes, int n_in,
                              void* d_out, int out_size, void* d_ws, size_t ws_size,
                              hipStream_t stream) {
    const float* qf     = (const float*)d_in[0];
    const int*   mask   = (const int*)d_in[1];
    const float* memory = (const float*)d_in[2];
    const float* Wq     = (const float*)d_in[3];
    const float* bq     = (const float*)d_in[4];
    const float* Wk     = (const float*)d_in[5];
    const float* bk     = (const float*)d_in[6];
    const float* Wv     = (const float*)d_in[7];
    const float* bv     = (const float*)d_in[8];
    const float* Wo     = (const float*)d_in[9];
    const float* bo     = (const float*)d_in[10];

    char* ws = (char*)d_ws;
    float* kproj  = (float*)ws;                  // 128 KB
    float* vproj  = (float*)(ws + 131072);       // 128 KB
    float* b2     = (float*)(ws + 262144);       // 2 KB
    char*  W2img  = ws + 264192;                 // 512 KB
    char*  W3img  = ws + 788480;                 // 512 KB
    char*  attn_p = ws + 1572864;                // step-image intermediate

    size_t avail = ws_size > 1572864 ? ws_size - 1572864 : 0;
    long mr = (long)(avail / 1024);              // 1 KB per row
    int rpc = (int)((mr / 128) * 128);
    if (rpc > NROWS) rpc = NROWS;
    if (rpc < 128) rpc = 128;

    prep_kv<<<64, 256, 0, stream>>>(memory, Wk, bk, Wv, bv, kproj, vproj);
    prep_w<<<512, 256, 0, stream>>>(Wq, bq, Wo, kproj, vproj, W2img, b2, W3img);

    for (int row0 = 0; row0 < NROWS; row0 += rpc) {
        int rows = NROWS - row0; if (rows > rpc) rows = rpc;
        const int nwg = (rows / 128) * 4;
        k1_gemm_sm<<<nwg, 256, 0, stream>>>(qf, mask, W2img, b2, attn_p, row0);
        k2_gemm_out<<<nwg, 256, 0, stream>>>(attn_p, W3img, bo, (float*)d_out, row0);
    }
}

// Round 14
// 267.300 us; speedup vs baseline: 1.6031x; 1.2801x over previous
//
#include <hip/hip_runtime.h>
#include <hip/hip_bf16.h>

#define DD 512
#define HDIM 64
#define NROWS 131072

typedef __bf16 bf16x8 __attribute__((ext_vector_type(8)));
typedef float f32x4 __attribute__((ext_vector_type(4)));

static __device__ __forceinline__ unsigned bfbits(float f) {
    union { float f; unsigned u; } x; x.f = f;
    unsigned r = x.u + 0x7fffu + ((x.u >> 16) & 1u);
    return r >> 16;
}
static __device__ __forceinline__ __bf16 to_bf16(float f) {
    union { unsigned short s; __bf16 b; } y; y.s = (unsigned short)bfbits(f); return y.b;
}

// Step-image element offset: p = row-or-col index, g = k-granule (8 bf16),
// e = elem. Double-XOR granule swizzle -> ds_read_b128 frag reads ~2-way.
static __device__ __forceinline__ int imgoff(int p, int g, int e) {
    return p * 64 + ((((g) ^ ((p) & 3) ^ (((p) >> 2) & 3)) & 3) << 4) + e * 2;
}

// Fragment-linear byte offset for a [512 cols][512 k] bf16 weight matrix (R7):
// addr = ((c>>6)*64 + (d>>5)*4 + ((c>>4)&3))*1024 + slot*16 + (d&7)*2,
// slot = ((d>>3)&3)*16 + (c&15).  A wave frag load = base + lane*16 (coalesced).
static __device__ __forceinline__ size_t fragoff(int c, int d) {
    return (size_t)((((c >> 6) * 64 + (d >> 5) * 4 + ((c >> 4) & 3)) << 10)
         + (((((d >> 3) & 3) << 4) + (c & 15)) << 4) + ((d & 7) << 1));
}

static __device__ __forceinline__ void gll16(const void* gsrc, void* ldst) {
    __builtin_amdgcn_global_load_lds(
        (const __attribute__((address_space(1))) unsigned int*)gsrc,
        (__attribute__((address_space(3))) unsigned int*)ldst, 16, 0, 0);
}

#define VMCNT(n) asm volatile("s_waitcnt vmcnt(" #n ")" ::: "memory")
#define LGKM0 asm volatile("s_waitcnt lgkmcnt(0)" ::: "memory")
#define MEMPIN asm volatile("" ::: "memory")   // pin VMEM issue order

// bijective XCD-chunk swizzle (m204); 2048 % 8 == 0 -> simple form is exact
static __device__ __forceinline__ int xcd_swz(int bid, int nwg) {
    const int q = nwg >> 3, r = nwg & 7;
    const int xcd = bid & 7, idx = bid >> 3;
    return (xcd < r ? xcd * (q + 1) : r * (q + 1) + (xcd - r) * q) + idx;
}

// ---------------- prep 1: k/v projections of memory (tiny) ----------------
__global__ void prep_kv(const float* __restrict__ memory,
                        const float* __restrict__ Wk, const float* __restrict__ bk,
                        const float* __restrict__ Wv, const float* __restrict__ bv,
                        float* __restrict__ kproj, float* __restrict__ vproj) {
    __shared__ float mrow[DD];
    const int m = blockIdx.x;
    const int t = threadIdx.x;
    for (int i = t; i < DD; i += 256) mrow[i] = memory[(size_t)m * DD + i];
    __syncthreads();
    for (int jj = 0; jj < 2; ++jj) {
        const int j = t + jj * 256;
        const float* wkr = Wk + (size_t)j * DD;
        const float* wvr = Wv + (size_t)j * DD;
        float sk = 0.f, sv = 0.f;
        for (int d = 0; d < DD; ++d) {
            const float md = mrow[d];
            sk += md * wkr[d];
            sv += md * wvr[d];
        }
        kproj[(size_t)m * DD + j] = sk + bk[j];
        vproj[(size_t)m * DD + j] = sv + bv[j];
    }
}

// ---------------- prep 2: fold into W2img (step images) / b2 / W3fr ----------
// W2img: 16 steps x 32KB; step s holds all 512 score-cols c, k-dims d=32s..+31.
// W3fr : fragment-linear [out-col j][k-dim c].
__global__ void prep_w(const float* __restrict__ Wq, const float* __restrict__ bq,
                       const float* __restrict__ Wo,
                       const float* __restrict__ kproj, const float* __restrict__ vproj,
                       char* __restrict__ W2img, float* __restrict__ b2,
                       char* __restrict__ W3fr) {
    const int i = blockIdx.x;   // c (score-col) for W2img/b2; j (out-col) for W3fr
    const int t = threadIdx.x;
    __shared__ float kp[HDIM];
    __shared__ float worow[DD];
    const int m = i & 63, h = i >> 6;
    if (t < HDIM) kp[t] = kproj[(size_t)m * DD + h * HDIM + t];
    for (int d = t; d < DD; d += 256) worow[d] = Wo[(size_t)i * DD + d];
    __syncthreads();
    for (int dd2 = 0; dd2 < 2; ++dd2) {
        const int d = t + dd2 * 256;
        float s = 0.f;
        #pragma unroll 8
        for (int hd = 0; hd < HDIM; ++hd)
            s += Wq[(size_t)(h * HDIM + hd) * DD + d] * kp[hd];
        *(__bf16*)(W2img + (size_t)(d >> 5) * 32768 + imgoff(i, (d >> 3) & 3, d & 7)) = to_bf16(s);
    }
    if (t == 0) {
        float s = 0.f;
        for (int hd = 0; hd < HDIM; ++hd) s += bq[h * HDIM + hd] * kp[hd];
        b2[i] = s;
    }
    for (int cc = 0; cc < 2; ++cc) {
        const int c = t + cc * 256;
        const int mc = c & 63, hc = c >> 6;
        float s = 0.f;
        #pragma unroll 8
        for (int hd = 0; hd < HDIM; ++hd)
            s += vproj[(size_t)mc * DD + hc * HDIM + hd] * worow[hc * HDIM + hd];
        *(__bf16*)(W3fr + fragoff(i, c)) = to_bf16(s);
    }
}

// ---------------- fused kernel: x@W2 + b2 -> softmax -> @W3 + bo -> out -------
// Block: 64 rows x 512 cols, 4 waves; wave wn = 64 rows x cols [wn*128, +128)
// = heads 2wn, 2wn+1 (softmax wave-local). acc[4][8] = 128 AGPR.
// LDS 72KB: A-x images dbuf 2x4KB @0; B-W2 images dbuf 2x32KB @8192.
// Phase 2 reuses the 64KB B region for 16 attn step-images (4KB each).
// Phase 3 streams W3 frag-linear from L2 into registers (no LDS, no barriers).
__global__ __launch_bounds__(256, 2) void attn_fused(
    const float* __restrict__ x, const int* __restrict__ mask,
    const char* __restrict__ W2img, const float* __restrict__ b2,
    const char* __restrict__ W3fr, const float* __restrict__ bo,
    float* __restrict__ out) {
    __shared__ char ldsb[73728];

    const int tid = threadIdx.x;
    const int lane = tid & 63;
    const int wn = tid >> 6;              // 0..3: col quarter (2 heads)
    const int lc = lane & 15, grp = lane >> 4;
    const int swz = xcd_swz(blockIdx.x, gridDim.x);
    const int gr0 = swz * 64;

    // ---- A (x) staging: thread -> (row, granule); 32B fp32 load, 16B bf16 write
    const int arow = tid >> 2, ag = tid & 3;
    const float* asrc = x + (size_t)(gr0 + arow) * DD + ag * 8;
    const int adst = imgoff(arow, ag, 0);
    const char* bsrc = W2img + wn * 8192 + lane * 16;

    f32x4 sreg[2][2];
    #define ALOAD(kt, set)                                                         \
        { sreg[set][0] = *(const f32x4*)(asrc + (kt) * 32);                        \
          sreg[set][1] = *(const f32x4*)(asrc + (kt) * 32 + 4); }
    #define AWRITE(buf, set)                                                       \
        { uint4 u;                                                                 \
          u.x = bfbits(sreg[set][0][0]) | (bfbits(sreg[set][0][1]) << 16);         \
          u.y = bfbits(sreg[set][0][2]) | (bfbits(sreg[set][0][3]) << 16);         \
          u.z = bfbits(sreg[set][1][0]) | (bfbits(sreg[set][1][1]) << 16);         \
          u.w = bfbits(sreg[set][1][2]) | (bfbits(sreg[set][1][3]) << 16);         \
          *(uint4*)(ldsb + (buf) * 4096 + adst) = u; }
    #define BGLL(kt, buf)                                                          \
        { _Pragma("unroll")                                                        \
          for (int g = 0; g < 8; ++g)                                              \
              gll16(bsrc + (size_t)(kt) * 32768 + g * 1024,                        \
                    ldsb + 8192 + (buf) * 32768 + wn * 8192 + g * 1024); }
    // frag reads (swizzle XOR is per-lane compile-time per m/n)
    #define LDA1(buf, m)                                                           \
        (*(const bf16x8*)(ldsb + (buf) * 4096 + ((m) * 16 + lc) * 64               \
            + (((grp ^ (lc & 3) ^ (((m) * 4 + (lc >> 2)) & 3)) & 3) << 4)))
    #define LDB1(buf, n)                                                           \
        (*(const bf16x8*)(ldsb + 8192 + (buf) * 32768                              \
            + (wn * 128 + (n) * 16 + lc) * 64                                      \
            + (((grp ^ (lc & 3) ^ (((n) * 4 + (lc >> 2)) & 3)) & 3) << 4)))

    f32x4 acc[4][8];
    #pragma unroll
    for (int m = 0; m < 4; ++m)
        #pragma unroll
        for (int n = 0; n < 8; ++n) acc[m][n] = (f32x4){0.f, 0.f, 0.f, 0.f};

    // ---- phase 1 prologue (MEMPIN pins VMEM issue order so counted vmcnt
    // retirement (oldest-first) matches program order)
    BGLL(0, 0);
    MEMPIN;
    ALOAD(0, 0);
    MEMPIN;
    ALOAD(1, 1);
    VMCNT(2);          // B0 + A0 done; A1 (2 loads) in flight
    AWRITE(0, 0);
    LGKM0;
    __builtin_amdgcn_s_barrier();
    __builtin_amdgcn_sched_barrier(0);

    // ---- phase 1 K-loop: S = x @ W2
    #pragma unroll
    for (int s = 0; s < 16; ++s) {
        const int p = s & 1;
        if (s < 15) BGLL(s + 1, p ^ 1);
        MEMPIN;
        if (s < 14) ALOAD(s + 2, s & 1);
        bf16x8 af[4], bf[8];
        #pragma unroll
        for (int m = 0; m < 4; ++m) af[m] = LDA1(p, m);
        #pragma unroll
        for (int n = 0; n < 8; ++n) bf[n] = LDB1(p, n);
        __builtin_amdgcn_s_setprio(1);
        #pragma unroll
        for (int m = 0; m < 4; ++m)
            #pragma unroll
            for (int n = 0; n < 8; ++n)
                acc[m][n] = __builtin_amdgcn_mfma_f32_16x16x32_bf16(af[m], bf[n], acc[m][n], 0, 0, 0);
        __builtin_amdgcn_s_setprio(0);
        if (s < 14) {
            VMCNT(2);                        // drain B(s+1) + A(s+1); leave A(s+2)
            AWRITE(p ^ 1, (s + 1) & 1);
            LGKM0;
            __builtin_amdgcn_s_barrier();
            __builtin_amdgcn_sched_barrier(0);
        } else if (s < 15) {
            VMCNT(0);
            AWRITE(p ^ 1, 1);
            LGKM0;
            __builtin_amdgcn_s_barrier();
            __builtin_amdgcn_sched_barrier(0);
        }
    }
    __syncthreads();   // all B reads done -> B region reusable for attn images
    #undef ALOAD
    #undef AWRITE
    #undef BGLL
    #undef LDA1
    #undef LDB1

    // ---- hoist phase-3 B(0) fragment loads (hide L2 latency under softmax)
    const char* b3 = W3fr + wn * 131072 + lane * 16;
    #define LB3(kt, buf)                                                           \
        { _Pragma("unroll")                                                        \
          for (int n = 0; n < 8; ++n)                                              \
              bb3[buf][n] = *(const bf16x8*)(b3 + ((n) >> 2) * 65536               \
                  + (size_t)(kt) * 4096 + ((n) & 3) * 1024); }
    bf16x8 bb3[2][8];
    LB3(0, 0);

    // ---- phase 2: softmax (wave-local heads) -> attn step-images in B region
    float b2v[8];
    #pragma unroll
    for (int n = 0; n < 8; ++n) b2v[n] = b2[wn * 128 + n * 16 + lc];

    #pragma unroll
    for (int m = 0; m < 4; ++m) {
        const int4 mv = *(const int4*)(mask + gr0 + m * 16 + grp * 4);
        const int mk[4] = {mv.x, mv.y, mv.z, mv.w};
        #pragma unroll
        for (int hl = 0; hl < 2; ++hl) {
            #pragma unroll
            for (int j = 0; j < 4; ++j) {
                float s0 = (acc[m][hl * 4 + 0][j] + b2v[hl * 4 + 0]) * 0.125f;
                float s1 = (acc[m][hl * 4 + 1][j] + b2v[hl * 4 + 1]) * 0.125f;
                float s2 = (acc[m][hl * 4 + 2][j] + b2v[hl * 4 + 2]) * 0.125f;
                float s3 = (acc[m][hl * 4 + 3][j] + b2v[hl * 4 + 3]) * 0.125f;
                float mx = fmaxf(fmaxf(s0, s1), fmaxf(s2, s3));
                mx = fmaxf(mx, __shfl_xor(mx, 1));
                mx = fmaxf(mx, __shfl_xor(mx, 2));
                mx = fmaxf(mx, __shfl_xor(mx, 4));
                mx = fmaxf(mx, __shfl_xor(mx, 8));
                float p0 = __expf(s0 - mx);
                float p1 = __expf(s1 - mx);
                float p2 = __expf(s2 - mx);
                float p3 = __expf(s3 - mx);
                float sm = (p0 + p1) + (p2 + p3);
                sm += __shfl_xor(sm, 1);
                sm += __shfl_xor(sm, 2);
                sm += __shfl_xor(sm, 4);
                sm += __shfl_xor(sm, 8);
                float a[4];
                if (mk[j] == 0) {
                    a[0] = a[1] = a[2] = a[3] = 0.015625f;   // fp32 -1e9 bias -> uniform attn
                } else {
                    const float inv = 1.0f / sm;
                    a[0] = p0 * inv; a[1] = p1 * inv; a[2] = p2 * inv; a[3] = p3 * inv;
                }
                const int rl = m * 16 + grp * 4 + j;
                #pragma unroll
                for (int q = 0; q < 4; ++q) {
                    const int n = hl * 4 + q;
                    const int si = wn * 4 + (n >> 1);                 // image index
                    const int g2 = (n & 1) * 2 + (lc >> 3);           // k granule
                    const int off = 8192 + si * 4096 + rl * 64
                        + (((g2 ^ (rl & 3) ^ ((rl >> 2) & 3)) & 3) << 4)
                        + ((lc & 7) << 1);
                    *(short*)(ldsb + off) = (short)bfbits(a[q]);      // FIX: a[q], not a[n]
                }
            }
        }
    }
    __syncthreads();   // attn images complete

    // ---- phase 3: out = attn @ W3 (A from LDS images, B reg-streamed), no barriers
    #define LDA3(s, m)                                                             \
        (*(const bf16x8*)(ldsb + 8192 + (s) * 4096 + ((m) * 16 + lc) * 64          \
            + (((grp ^ (lc & 3) ^ (((m) * 4 + (lc >> 2)) & 3)) & 3) << 4)))

    #pragma unroll
    for (int m = 0; m < 4; ++m)
        #pragma unroll
        for (int n = 0; n < 8; ++n) acc[m][n] = (f32x4){0.f, 0.f, 0.f, 0.f};

    #pragma unroll
    for (int s = 0; s < 16; ++s) {
        const int p = s & 1;
        if (s < 15) LB3(s + 1, p ^ 1);
        bf16x8 af[4];
        #pragma unroll
        for (int m = 0; m < 4; ++m) af[m] = LDA3(s, m);
        __builtin_amdgcn_s_setprio(1);
        #pragma unroll
        for (int m = 0; m < 4; ++m)
            #pragma unroll
            for (int n = 0; n < 8; ++n)
                acc[m][n] = __builtin_amdgcn_mfma_f32_16x16x32_bf16(af[m], bb3[p][n], acc[m][n], 0, 0, 0);
        __builtin_amdgcn_s_setprio(0);
    }
    #undef LB3
    #undef LDA3

    // ---- epilogue: + bo, non-temporal row-major stores
    float bov[8];
    #pragma unroll
    for (int n = 0; n < 8; ++n) bov[n] = bo[wn * 128 + n * 16 + lc];

    #pragma unroll
    for (int m = 0; m < 4; ++m) {
        #pragma unroll
        for (int j = 0; j < 4; ++j) {
            const int gr = gr0 + m * 16 + grp * 4 + j;
            float* orow = out + (size_t)gr * DD + wn * 128 + lc;
            #pragma unroll
            for (int n = 0; n < 8; ++n)
                __builtin_nontemporal_store(acc[m][n][j] + bov[n], orow + n * 16);
        }
    }
}

extern "C" void kernel_launch(void* const* d_in, const int* in_sizes, int n_in,
                              void* d_out, int out_size, void* d_ws, size_t ws_size,
                              hipStream_t stream) {
    const float* qf     = (const float*)d_in[0];
    const int*   mask   = (const int*)d_in[1];
    const float* memory = (const float*)d_in[2];
    const float* Wq     = (const float*)d_in[3];
    const float* bq     = (const float*)d_in[4];
    const float* Wk     = (const float*)d_in[5];
    const float* bk     = (const float*)d_in[6];
    const float* Wv     = (const float*)d_in[7];
    const float* bv     = (const float*)d_in[8];
    const float* Wo     = (const float*)d_in[9];
    const float* bo     = (const float*)d_in[10];

    char* ws = (char*)d_ws;
    float* kproj = (float*)ws;                   // 128 KB
    float* vproj = (float*)(ws + 131072);        // 128 KB
    float* b2    = (float*)(ws + 262144);        // 2 KB
    char*  W2img = ws + 264192;                  // 512 KB (16 step-images)
    char*  W3fr  = ws + 788480;                  // 512 KB (fragment-linear)

    prep_kv<<<64, 256, 0, stream>>>(memory, Wk, bk, Wv, bv, kproj, vproj);
    prep_w<<<512, 256, 0, stream>>>(Wq, bq, Wo, kproj, vproj, W2img, b2, W3fr);
    attn_fused<<<NROWS / 64, 256, 0, stream>>>(qf, mask, W2img, b2, W3fr, bo, (float*)d_out);
}